// Round 1
// baseline (1198.735 us; speedup 1.0000x reference)
//
#include <hip/hip_runtime.h>

#define FIN 256
#define FH  64

// ---------------- degree / normalization ----------------

__global__ __launch_bounds__(256) void deg_kernel(const int* __restrict__ rows,
                                                  unsigned* __restrict__ deg, int E) {
    int e = blockIdx.x * 256 + threadIdx.x;
    if (e < E) atomicAdd(&deg[rows[e]], 1u);
}

__global__ __launch_bounds__(256) void dis_kernel(const unsigned* __restrict__ deg,
                                                  float* __restrict__ dis, int N) {
    int i = blockIdx.x * 256 + threadIdx.x;
    if (i < N) {
        unsigned d = deg[i];
        dis[i] = d ? 1.0f / sqrtf((float)d) : 0.0f;
    }
}

// ---------------- GEMM1: out[N][64] = x[N][256] @ W[256][64] + b ----------------
// 256 threads, 256-row tile, per-thread 8 rows x 8 cols, K-chunk 32.
__global__ __launch_bounds__(256) void gemm1_kernel(const float* __restrict__ x,
                                                    const float* __restrict__ W,
                                                    const float* __restrict__ b,
                                                    float* __restrict__ out, int N) {
    __shared__ float xs[32][260];   // transposed x chunk, stride 260 breaks conflicts, keeps 16B align
    __shared__ float ws[32][64];
    const int t = threadIdx.x;
    const int rb = blockIdx.x * 256;
    const int rg = t >> 3, cg = t & 7;
    const int r0 = rg * 8, c0 = cg * 8;
    float acc[8][8];
#pragma unroll
    for (int i = 0; i < 8; ++i)
#pragma unroll
        for (int j = 0; j < 8; ++j) acc[i][j] = 0.f;

    const float4* x4 = (const float4*)x;
    const int kk = (t & 7) * 4;   // k sub-offset this thread stages
    const int rloc = t >> 3;      // row sub-offset

    for (int k0 = 0; k0 < FIN; k0 += 32) {
        __syncthreads();
        // stage W chunk [32][64] (contiguous region)
        {
            const float4* w4 = (const float4*)(W + k0 * 64);
            float4* wl = (float4*)&ws[0][0];
            wl[t]       = w4[t];
            wl[t + 256] = w4[t + 256];
        }
        // stage x chunk transposed: rows rb..rb+255, k = k0..k0+31
#pragma unroll
        for (int p = 0; p < 8; ++p) {
            int r = rloc + p * 32;
            int gr = rb + r; if (gr >= N) gr = N - 1;   // clamp; stores guarded later
            float4 v = x4[gr * 64 + (k0 >> 2) + (t & 7)];
            xs[kk + 0][r] = v.x; xs[kk + 1][r] = v.y;
            xs[kk + 2][r] = v.z; xs[kk + 3][r] = v.w;
        }
        __syncthreads();
#pragma unroll
        for (int k = 0; k < 32; ++k) {
            float4 xa = *(const float4*)&xs[k][r0];
            float4 xb = *(const float4*)&xs[k][r0 + 4];
            float4 wa = *(const float4*)&ws[k][c0];
            float4 wb = *(const float4*)&ws[k][c0 + 4];
            float xr[8] = {xa.x, xa.y, xa.z, xa.w, xb.x, xb.y, xb.z, xb.w};
            float wr[8] = {wa.x, wa.y, wa.z, wa.w, wb.x, wb.y, wb.z, wb.w};
#pragma unroll
            for (int i = 0; i < 8; ++i)
#pragma unroll
                for (int j = 0; j < 8; ++j) acc[i][j] = fmaf(xr[i], wr[j], acc[i][j]);
        }
    }
    float bias[8];
#pragma unroll
    for (int j = 0; j < 8; ++j) bias[j] = b[c0 + j];
#pragma unroll
    for (int i = 0; i < 8; ++i) {
        int gr = rb + r0 + i;
        if (gr < N) {
            float4 o0, o1;
            o0.x = acc[i][0] + bias[0]; o0.y = acc[i][1] + bias[1];
            o0.z = acc[i][2] + bias[2]; o0.w = acc[i][3] + bias[3];
            o1.x = acc[i][4] + bias[4]; o1.y = acc[i][5] + bias[5];
            o1.z = acc[i][6] + bias[6]; o1.w = acc[i][7] + bias[7];
            *(float4*)&out[gr * 64 + c0]     = o0;
            *(float4*)&out[gr * 64 + c0 + 4] = o1;
        }
    }
}

// ---------------- scatter aggregation: out[row] += dis[col] * h[col] ----------------
// one 64-lane wave per edge, lane = feature
__global__ __launch_bounds__(256) void agg_kernel(const int* __restrict__ rows,
                                                  const int* __restrict__ cols,
                                                  const float* __restrict__ dis,
                                                  const float* __restrict__ h,
                                                  float* __restrict__ out, int E) {
    int e = blockIdx.x * 4 + (threadIdx.x >> 6);
    int lane = threadIdx.x & 63;
    if (e >= E) return;
    int r = rows[e], c = cols[e];
    float v = dis[c] * h[c * 64 + lane];
    atomicAdd(&out[r * 64 + lane], v);
}

// ---------------- GEMM2: out[N][64] = relu(dis[r]*agg[r][:]) @ W[64][64] + b ----------------
// 256 threads, 128-row tile, per-thread 4 rows x 8 cols, single K=64 chunk.
__global__ __launch_bounds__(256) void gemm2_kernel(const float* __restrict__ agg,
                                                    const float* __restrict__ dis,
                                                    const float* __restrict__ W,
                                                    const float* __restrict__ b,
                                                    float* __restrict__ out, int N) {
    __shared__ float xs[64][132];
    __shared__ float ws[64][64];
    const int t = threadIdx.x;
    const int rb = blockIdx.x * 128;
    // stage W (64x64 = 1024 float4)
    {
        const float4* w4 = (const float4*)W;
        float4* wl = (float4*)&ws[0][0];
#pragma unroll
        for (int p = 0; p < 4; ++p) wl[p * 256 + t] = w4[p * 256 + t];
    }
    // stage x = relu(dis[r] * agg[r][c]), transposed
    {
        const float4* a4 = (const float4*)agg;
        const int c4 = (t & 15) * 4;
        const int rloc = t >> 4;
#pragma unroll
        for (int p = 0; p < 8; ++p) {
            int r = rloc + p * 16;
            int gr = rb + r; if (gr >= N) gr = N - 1;
            float d = dis[gr];
            float4 v = a4[gr * 16 + (t & 15)];
            xs[c4 + 0][r] = fmaxf(v.x * d, 0.f);
            xs[c4 + 1][r] = fmaxf(v.y * d, 0.f);
            xs[c4 + 2][r] = fmaxf(v.z * d, 0.f);
            xs[c4 + 3][r] = fmaxf(v.w * d, 0.f);
        }
    }
    __syncthreads();
    const int rg = t >> 3, cg = t & 7;
    const int r0 = rg * 4, c0 = cg * 8;
    float acc[4][8];
#pragma unroll
    for (int i = 0; i < 4; ++i)
#pragma unroll
        for (int j = 0; j < 8; ++j) acc[i][j] = 0.f;
#pragma unroll 16
    for (int k = 0; k < 64; ++k) {
        float4 xa = *(const float4*)&xs[k][r0];
        float4 wa = *(const float4*)&ws[k][c0];
        float4 wb = *(const float4*)&ws[k][c0 + 4];
        float xr[4] = {xa.x, xa.y, xa.z, xa.w};
        float wr[8] = {wa.x, wa.y, wa.z, wa.w, wb.x, wb.y, wb.z, wb.w};
#pragma unroll
        for (int i = 0; i < 4; ++i)
#pragma unroll
            for (int j = 0; j < 8; ++j) acc[i][j] = fmaf(xr[i], wr[j], acc[i][j]);
    }
    float bias[8];
#pragma unroll
    for (int j = 0; j < 8; ++j) bias[j] = b[c0 + j];
#pragma unroll
    for (int i = 0; i < 4; ++i) {
        int gr = rb + r0 + i;
        if (gr < N) {
            float4 o0, o1;
            o0.x = acc[i][0] + bias[0]; o0.y = acc[i][1] + bias[1];
            o0.z = acc[i][2] + bias[2]; o0.w = acc[i][3] + bias[3];
            o1.x = acc[i][4] + bias[4]; o1.y = acc[i][5] + bias[5];
            o1.z = acc[i][6] + bias[6]; o1.w = acc[i][7] + bias[7];
            *(float4*)&out[gr * 64 + c0]     = o0;
            *(float4*)&out[gr * 64 + c0 + 4] = o1;
        }
    }
}

// ---------------- decode: out[e] = dis[a]*dis[b] * dot64(agg2[a], agg2[b]) ----------------
// 16 lanes per edge, float4 per lane, shfl_xor reduce within 16-lane group.
__global__ __launch_bounds__(256) void decode_kernel(const int* __restrict__ pe,
                                                     const int* __restrict__ ne,
                                                     const float* __restrict__ dis,
                                                     const float* __restrict__ z,
                                                     float* __restrict__ out, int Ep, int En) {
    const int t = threadIdx.x;
    const int grp = t >> 4;      // 0..15
    const int l16 = t & 15;
    int e = blockIdx.x * 16 + grp;
    int Etot = Ep + En;
    if (e >= Etot) return;
    int a, b;
    if (e < Ep) { a = pe[e]; b = pe[Ep + e]; }
    else        { int j = e - Ep; a = ne[j]; b = ne[En + j]; }
    const float4* z4 = (const float4*)z;
    float4 va = z4[a * 16 + l16];
    float4 vb = z4[b * 16 + l16];
    float s = va.x * vb.x + va.y * vb.y + va.z * vb.z + va.w * vb.w;
    s += __shfl_xor(s, 8);
    s += __shfl_xor(s, 4);
    s += __shfl_xor(s, 2);
    s += __shfl_xor(s, 1);
    if (l16 == 0) out[e] = dis[a] * dis[b] * s;
}

// ---------------- launch ----------------

extern "C" void kernel_launch(void* const* d_in, const int* in_sizes, int n_in,
                              void* d_out, int out_size, void* d_ws, size_t ws_size,
                              hipStream_t stream) {
    const float* x  = (const float*)d_in[0];
    const int*   pe = (const int*)d_in[1];
    const int*   ne = (const int*)d_in[2];
    const float* W1 = (const float*)d_in[3];
    const float* b1 = (const float*)d_in[4];
    const float* W2 = (const float*)d_in[5];
    const float* b2 = (const float*)d_in[6];
    float* outp = (float*)d_out;

    const int N  = in_sizes[0] / FIN;
    const int Ep = in_sizes[1] / 2;
    const int En = in_sizes[2] / 2;

    char* w = (char*)d_ws;
    size_t off = 0;
    auto alloc = [&](size_t bytes) {
        void* p = w + off;
        off = (off + bytes + 255) & ~(size_t)255;
        return p;
    };
    unsigned* deg = (unsigned*)alloc((size_t)N * 4);
    float* dis = (float*)alloc((size_t)N * 4);
    float* A   = (float*)alloc((size_t)N * 64 * 4);   // h, then h2
    float* B   = (float*)alloc((size_t)N * 64 * 4);   // agg1, then agg2

    hipMemsetAsync(deg, 0, (size_t)N * 4, stream);
    hipMemsetAsync(B, 0, (size_t)N * 64 * 4, stream);

    deg_kernel<<<(Ep + 255) / 256, 256, 0, stream>>>(pe, deg, Ep);
    dis_kernel<<<(N + 255) / 256, 256, 0, stream>>>(deg, dis, N);
    gemm1_kernel<<<(N + 255) / 256, 256, 0, stream>>>(x, W1, b1, A, N);
    agg_kernel<<<(Ep + 3) / 4, 256, 0, stream>>>(pe, pe + Ep, dis, A, B, Ep);
    gemm2_kernel<<<(N + 127) / 128, 256, 0, stream>>>(B, dis, W2, b2, A, N);
    hipMemsetAsync(B, 0, (size_t)N * 64 * 4, stream);
    agg_kernel<<<(Ep + 3) / 4, 256, 0, stream>>>(pe, pe + Ep, dis, A, B, Ep);
    decode_kernel<<<(Ep + En + 15) / 16, 256, 0, stream>>>(pe, ne, dis, B, outp, Ep, En);
}

// Round 3
// 755.588 us; speedup vs baseline: 1.5865x; 1.5865x over previous
//
#include <hip/hip_runtime.h>

#define FIN 256
#define FH  64
#define SCAN_BLK 1024

// ---------------- degree / normalization ----------------

__global__ __launch_bounds__(256) void deg_kernel(const int* __restrict__ rows,
                                                  unsigned* __restrict__ deg, int E) {
    int e = blockIdx.x * 256 + threadIdx.x;
    if (e < E) atomicAdd(&deg[rows[e]], 1u);
}

__global__ __launch_bounds__(256) void dis_kernel(const unsigned* __restrict__ deg,
                                                  float* __restrict__ dis, int N) {
    int i = blockIdx.x * 256 + threadIdx.x;
    if (i < N) {
        unsigned d = deg[i];
        dis[i] = d ? 1.0f / sqrtf((float)d) : 0.0f;
    }
}

// ---------------- exclusive scan of deg -> rowptr (3 kernels) ----------------

__global__ __launch_bounds__(256) void scan_block_kernel(const unsigned* __restrict__ deg,
                                                         int* __restrict__ rowptr,
                                                         int* __restrict__ blocksums, int N) {
    __shared__ int wsum[4];
    const int t = threadIdx.x;
    const int base = blockIdx.x * SCAN_BLK + t * 4;
    int d0 = 0, d1 = 0, d2 = 0, d3 = 0;
    if (base + 0 < N) d0 = (int)deg[base + 0];
    if (base + 1 < N) d1 = (int)deg[base + 1];
    if (base + 2 < N) d2 = (int)deg[base + 2];
    if (base + 3 < N) d3 = (int)deg[base + 3];
    const int tot = d0 + d1 + d2 + d3;
    const int lane = t & 63, wv = t >> 6;
    int inc = tot;
#pragma unroll
    for (int off = 1; off < 64; off <<= 1) {
        int v = __shfl_up(inc, off, 64);
        if (lane >= off) inc += v;
    }
    if (lane == 63) wsum[wv] = inc;
    __syncthreads();
    int woff = 0;
    for (int w = 0; w < wv; ++w) woff += wsum[w];
    const int ex = woff + inc - tot;   // exclusive prefix of this thread within block
    if (base + 0 < N) rowptr[base + 0] = ex;
    if (base + 1 < N) rowptr[base + 1] = ex + d0;
    if (base + 2 < N) rowptr[base + 2] = ex + d0 + d1;
    if (base + 3 < N) rowptr[base + 3] = ex + d0 + d1 + d2;
    if (t == 255) blocksums[blockIdx.x] = woff + inc;   // block total
}

__global__ void scan_sums_kernel(int* __restrict__ blocksums, int nb) {
    if (threadIdx.x == 0 && blockIdx.x == 0) {
        int run = 0;
        for (int i = 0; i < nb; ++i) { int v = blocksums[i]; blocksums[i] = run; run += v; }
    }
}

__global__ __launch_bounds__(256) void scan_add_kernel(int* __restrict__ rowptr,
                                                       int* __restrict__ cursor,
                                                       const int* __restrict__ blocksums,
                                                       int N, int E) {
    int i = blockIdx.x * 256 + threadIdx.x;
    if (i < N) {
        int v = rowptr[i] + blocksums[i / SCAN_BLK];
        rowptr[i] = v;
        cursor[i] = v;
    }
    if (i == 0) rowptr[N] = E;
}

// ---------------- counting-sort edges into CSR col array ----------------

__global__ __launch_bounds__(256) void scatter_edges_kernel(const int* __restrict__ rows,
                                                            const int* __restrict__ cols,
                                                            int* __restrict__ cursor,
                                                            int* __restrict__ colsorted, int E) {
    int e = blockIdx.x * 256 + threadIdx.x;
    if (e < E) {
        int p = atomicAdd(&cursor[rows[e]], 1);
        colsorted[p] = cols[e];
    }
}

// ---------------- GEMM1: out[N][64] = (x[N][256] @ W[256][64] + b) * dis[r] ----------------

__global__ __launch_bounds__(256) void gemm1_kernel(const float* __restrict__ x,
                                                    const float* __restrict__ W,
                                                    const float* __restrict__ b,
                                                    const float* __restrict__ dis,
                                                    float* __restrict__ out, int N) {
    __shared__ float xs[32][260];
    __shared__ float ws[32][64];
    const int t = threadIdx.x;
    const int rb = blockIdx.x * 256;
    const int rg = t >> 3, cg = t & 7;
    const int r0 = rg * 8, c0 = cg * 8;
    float acc[8][8];
#pragma unroll
    for (int i = 0; i < 8; ++i)
#pragma unroll
        for (int j = 0; j < 8; ++j) acc[i][j] = 0.f;

    const float4* x4 = (const float4*)x;
    const int kk = (t & 7) * 4;
    const int rloc = t >> 3;

    for (int k0 = 0; k0 < FIN; k0 += 32) {
        __syncthreads();
        {
            const float4* w4 = (const float4*)(W + k0 * 64);
            float4* wl = (float4*)&ws[0][0];
            wl[t]       = w4[t];
            wl[t + 256] = w4[t + 256];
        }
#pragma unroll
        for (int p = 0; p < 8; ++p) {
            int r = rloc + p * 32;
            int gr = rb + r; if (gr >= N) gr = N - 1;
            float4 v = x4[gr * 64 + (k0 >> 2) + (t & 7)];
            xs[kk + 0][r] = v.x; xs[kk + 1][r] = v.y;
            xs[kk + 2][r] = v.z; xs[kk + 3][r] = v.w;
        }
        __syncthreads();
#pragma unroll
        for (int k = 0; k < 32; ++k) {
            float4 xa = *(const float4*)&xs[k][r0];
            float4 xb = *(const float4*)&xs[k][r0 + 4];
            float4 wa = *(const float4*)&ws[k][c0];
            float4 wb = *(const float4*)&ws[k][c0 + 4];
            float xr[8] = {xa.x, xa.y, xa.z, xa.w, xb.x, xb.y, xb.z, xb.w};
            float wr[8] = {wa.x, wa.y, wa.z, wa.w, wb.x, wb.y, wb.z, wb.w};
#pragma unroll
            for (int i = 0; i < 8; ++i)
#pragma unroll
                for (int j = 0; j < 8; ++j) acc[i][j] = fmaf(xr[i], wr[j], acc[i][j]);
        }
    }
    float bias[8];
#pragma unroll
    for (int j = 0; j < 8; ++j) bias[j] = b[c0 + j];
#pragma unroll
    for (int i = 0; i < 8; ++i) {
        int gr = rb + r0 + i;
        if (gr < N) {
            float d = dis[gr];
            float4 o0, o1;
            o0.x = (acc[i][0] + bias[0]) * d; o0.y = (acc[i][1] + bias[1]) * d;
            o0.z = (acc[i][2] + bias[2]) * d; o0.w = (acc[i][3] + bias[3]) * d;
            o1.x = (acc[i][4] + bias[4]) * d; o1.y = (acc[i][5] + bias[5]) * d;
            o1.z = (acc[i][6] + bias[6]) * d; o1.w = (acc[i][7] + bias[7]) * d;
            *(float4*)&out[gr * 64 + c0]     = o0;
            *(float4*)&out[gr * 64 + c0 + 4] = o1;
        }
    }
}

// ---------------- CSR gather aggregation: out[r] = sum over neighbors of h[c] ----------------
// one 64-lane wave per row, lane = feature; batch-load indices + shfl broadcast

__global__ __launch_bounds__(256) void gather_agg_kernel(const int* __restrict__ rowptr,
                                                         const int* __restrict__ cols,
                                                         const float* __restrict__ h,
                                                         float* __restrict__ out, int N) {
    int r = blockIdx.x * 4 + (threadIdx.x >> 6);
    int lane = threadIdx.x & 63;
    if (r >= N) return;
    int s = rowptr[r], e = rowptr[r + 1];
    float acc0 = 0.f, acc1 = 0.f;
    for (int base = s; base < e; base += 64) {
        int n = e - base; if (n > 64) n = 64;
        int idx = (lane < n) ? cols[base + lane] : 0;
        int j = 0;
        for (; j + 1 < n; j += 2) {
            int c0 = __shfl(idx, j, 64);
            int c1 = __shfl(idx, j + 1, 64);
            acc0 += h[(size_t)c0 * 64 + lane];
            acc1 += h[(size_t)c1 * 64 + lane];
        }
        if (j < n) {
            int c0 = __shfl(idx, j, 64);
            acc0 += h[(size_t)c0 * 64 + lane];
        }
    }
    out[(size_t)r * 64 + lane] = acc0 + acc1;
}

// ---------------- GEMM2: out[N][64] = (relu(dis[r]*agg[r]) @ W[64][64] + b) * dis[r] ----------------

__global__ __launch_bounds__(256) void gemm2_kernel(const float* __restrict__ agg,
                                                    const float* __restrict__ dis,
                                                    const float* __restrict__ W,
                                                    const float* __restrict__ b,
                                                    float* __restrict__ out, int N) {
    __shared__ float xs[64][132];
    __shared__ float ws[64][64];
    const int t = threadIdx.x;
    const int rb = blockIdx.x * 128;
    {
        const float4* w4 = (const float4*)W;
        float4* wl = (float4*)&ws[0][0];
#pragma unroll
        for (int p = 0; p < 4; ++p) wl[p * 256 + t] = w4[p * 256 + t];
    }
    {
        const float4* a4 = (const float4*)agg;
        const int c4 = (t & 15) * 4;
        const int rloc = t >> 4;
#pragma unroll
        for (int p = 0; p < 8; ++p) {
            int r = rloc + p * 16;
            int gr = rb + r; if (gr >= N) gr = N - 1;
            float d = dis[gr];
            float4 v = a4[gr * 16 + (t & 15)];
            xs[c4 + 0][r] = fmaxf(v.x * d, 0.f);
            xs[c4 + 1][r] = fmaxf(v.y * d, 0.f);
            xs[c4 + 2][r] = fmaxf(v.z * d, 0.f);
            xs[c4 + 3][r] = fmaxf(v.w * d, 0.f);
        }
    }
    __syncthreads();
    const int rg = t >> 3, cg = t & 7;
    const int r0 = rg * 4, c0 = cg * 8;
    float acc[4][8];
#pragma unroll
    for (int i = 0; i < 4; ++i)
#pragma unroll
        for (int j = 0; j < 8; ++j) acc[i][j] = 0.f;
#pragma unroll 16
    for (int k = 0; k < 64; ++k) {
        float4 xa = *(const float4*)&xs[k][r0];
        float4 wa = *(const float4*)&ws[k][c0];
        float4 wb = *(const float4*)&ws[k][c0 + 4];
        float xr[4] = {xa.x, xa.y, xa.z, xa.w};
        float wr[8] = {wa.x, wa.y, wa.z, wa.w, wb.x, wb.y, wb.z, wb.w};
#pragma unroll
        for (int i = 0; i < 4; ++i)
#pragma unroll
            for (int j = 0; j < 8; ++j) acc[i][j] = fmaf(xr[i], wr[j], acc[i][j]);
    }
    float bias[8];
#pragma unroll
    for (int j = 0; j < 8; ++j) bias[j] = b[c0 + j];
#pragma unroll
    for (int i = 0; i < 4; ++i) {
        int gr = rb + r0 + i;
        if (gr < N) {
            float d = dis[gr];
            float4 o0, o1;
            o0.x = (acc[i][0] + bias[0]) * d; o0.y = (acc[i][1] + bias[1]) * d;
            o0.z = (acc[i][2] + bias[2]) * d; o0.w = (acc[i][3] + bias[3]) * d;
            o1.x = (acc[i][4] + bias[4]) * d; o1.y = (acc[i][5] + bias[5]) * d;
            o1.z = (acc[i][6] + bias[6]) * d; o1.w = (acc[i][7] + bias[7]) * d;
            *(float4*)&out[gr * 64 + c0]     = o0;
            *(float4*)&out[gr * 64 + c0 + 4] = o1;
        }
    }
}

// ---------------- decode: out[e] = dis[a]*dis[b] * dot64(agg2[a], agg2[b]) ----------------
// agg2 carries the column-side dis factors; the row-side dis[a],dis[b] applied here.

__global__ __launch_bounds__(256) void decode_kernel(const int* __restrict__ pe,
                                                     const int* __restrict__ ne,
                                                     const float* __restrict__ dis,
                                                     const float* __restrict__ z,
                                                     float* __restrict__ out, int Ep, int En) {
    const int t = threadIdx.x;
    const int grp = t >> 4;
    const int l16 = t & 15;
    int e = blockIdx.x * 16 + grp;
    int Etot = Ep + En;
    if (e >= Etot) return;
    int a, b;
    if (e < Ep) { a = pe[e]; b = pe[Ep + e]; }
    else        { int j = e - Ep; a = ne[j]; b = ne[En + j]; }
    const float4* z4 = (const float4*)z;
    float4 va = z4[a * 16 + l16];
    float4 vb = z4[b * 16 + l16];
    float s = va.x * vb.x + va.y * vb.y + va.z * vb.z + va.w * vb.w;
    s += __shfl_xor(s, 8);
    s += __shfl_xor(s, 4);
    s += __shfl_xor(s, 2);
    s += __shfl_xor(s, 1);
    if (l16 == 0) out[e] = dis[a] * dis[b] * s;
}

// ---------------- launch ----------------

extern "C" void kernel_launch(void* const* d_in, const int* in_sizes, int n_in,
                              void* d_out, int out_size, void* d_ws, size_t ws_size,
                              hipStream_t stream) {
    const float* x  = (const float*)d_in[0];
    const int*   pe = (const int*)d_in[1];
    const int*   ne = (const int*)d_in[2];
    const float* W1 = (const float*)d_in[3];
    const float* b1 = (const float*)d_in[4];
    const float* W2 = (const float*)d_in[5];
    const float* b2 = (const float*)d_in[6];
    float* outp = (float*)d_out;

    const int N  = in_sizes[0] / FIN;
    const int Ep = in_sizes[1] / 2;
    const int En = in_sizes[2] / 2;

    char* w = (char*)d_ws;
    size_t off = 0;
    auto alloc = [&](size_t bytes) {
        void* p = w + off;
        off = (off + bytes + 255) & ~(size_t)255;
        return p;
    };
    unsigned* deg   = (unsigned*)alloc((size_t)N * 4);
    float* dis      = (float*)alloc((size_t)N * 4);
    int* rowptr     = (int*)alloc((size_t)(N + 1) * 4);
    int* cursor     = (int*)alloc((size_t)N * 4);
    int* blocksums  = (int*)alloc(((size_t)N / SCAN_BLK + 2) * 4);
    int* colsorted  = (int*)alloc((size_t)Ep * 4);
    float* A        = (float*)alloc((size_t)N * 64 * 4);   // h, then h2 (col-side dis folded)
    float* B        = (float*)alloc((size_t)N * 64 * 4);   // agg1, then agg2

    const int nscan = (N + SCAN_BLK - 1) / SCAN_BLK;

    hipMemsetAsync(deg, 0, (size_t)N * 4, stream);

    deg_kernel<<<(Ep + 255) / 256, 256, 0, stream>>>(pe, deg, Ep);
    dis_kernel<<<(N + 255) / 256, 256, 0, stream>>>(deg, dis, N);
    // CSR build
    scan_block_kernel<<<nscan, 256, 0, stream>>>(deg, rowptr, blocksums, N);
    scan_sums_kernel<<<1, 64, 0, stream>>>(blocksums, nscan);
    scan_add_kernel<<<(N + 255) / 256, 256, 0, stream>>>(rowptr, cursor, blocksums, N, Ep);
    scatter_edges_kernel<<<(Ep + 255) / 256, 256, 0, stream>>>(pe, pe + Ep, cursor, colsorted, Ep);
    // layer 1
    gemm1_kernel<<<(N + 255) / 256, 256, 0, stream>>>(x, W1, b1, dis, A, N);
    gather_agg_kernel<<<(N + 3) / 4, 256, 0, stream>>>(rowptr, colsorted, A, B, N);
    // layer 2
    gemm2_kernel<<<(N + 127) / 128, 256, 0, stream>>>(B, dis, W2, b2, A, N);
    gather_agg_kernel<<<(N + 3) / 4, 256, 0, stream>>>(rowptr, colsorted, A, B, N);
    // decode
    decode_kernel<<<(Ep + En + 15) / 16, 256, 0, stream>>>(pe, ne, dis, B, outp, Ep, En);
}